// Round 1
// baseline (22387.509 us; speedup 1.0000x reference)
//
#include <hip/hip_runtime.h>

// LSTM: x[64][512][512] fp32, U[512][4096], W[1024][4096], bias[4096]
// out = hidden_seq[64][512][1024] fp32 ++ h_T[64][1024] ++ c_T[64][1024]
//
// Structure:
//  Phase A (parallel): cast x->f16; pack W,U into per-lane MFMA B-fragment order (f16).
//  Phase B (persistent, 256 WGs x 256 thr): 4 batch-groups x 16 batches; each group
//  = 64 WGs, one 16-wide h-column tile each; wave q of a WG computes gate section q.
//  Per step: gates = bias + x_t@U + h@W via mfma_f32_16x16x32_f16 (W,U register-resident),
//  elementwise in fp32 (c in a register/thread), h exchanged via double-buffered global
//  f16 buffer + per-group atomic-counter barrier with threadfence release/acquire.

typedef _Float16 f16x8 __attribute__((ext_vector_type(8)));
typedef float f32x4 __attribute__((ext_vector_type(4)));

__device__ __forceinline__ unsigned short f2h_bits(float f) {
  union { _Float16 h; unsigned short u; } cv;
  cv.h = (_Float16)f;
  return cv.u;
}

// ---- Phase A kernels ------------------------------------------------------

// cast x fp32 -> f16 (16,777,216 elems, 4/thread)
__global__ void cast_x_kernel(const float* __restrict__ x, unsigned short* __restrict__ xh) {
  int i = blockIdx.x * 256 + threadIdx.x;            // [0, 4194304)
  float4 v = ((const float4*)x)[i];
  ushort4 o;
  o.x = f2h_bits(v.x); o.y = f2h_bits(v.y);
  o.z = f2h_bits(v.z); o.w = f2h_bits(v.w);
  ((ushort4*)xh)[i] = o;
}

// Pack W[1024][4096] into B-fragment stream:
// Wp[((T*32+kt)*64+l)*8 + j] = f16(W[(kt*32 + (l>>4)*8 + j)][ (T>>6)*1024 + (T&63)*16 + (l&15) ])
__global__ void pack_W_kernel(const float* __restrict__ W, unsigned short* __restrict__ Wp) {
  int idx = blockIdx.x * 256 + threadIdx.x;          // [0, 524288)
  int l  = idx & 63;
  int kt = (idx >> 6) & 31;
  int T  = idx >> 11;                                // 0..255
  int q = T >> 6, jt = T & 63;
  int g  = q * 1024 + jt * 16 + (l & 15);
  int kb = kt * 32 + ((l >> 4) << 3);
  unsigned short tmp[8];
#pragma unroll
  for (int j = 0; j < 8; ++j) tmp[j] = f2h_bits(W[(size_t)(kb + j) * 4096 + g]);
  ((uint4*)Wp)[idx] = *(const uint4*)tmp;
}

// Pack U[512][4096] likewise (16 k-tiles)
__global__ void pack_U_kernel(const float* __restrict__ U, unsigned short* __restrict__ Up) {
  int idx = blockIdx.x * 256 + threadIdx.x;          // [0, 262144)
  int l  = idx & 63;
  int kt = (idx >> 6) & 15;
  int T  = idx >> 10;                                // 0..255
  int q = T >> 6, jt = T & 63;
  int g  = q * 1024 + jt * 16 + (l & 15);
  int kb = kt * 32 + ((l >> 4) << 3);
  unsigned short tmp[8];
#pragma unroll
  for (int j = 0; j < 8; ++j) tmp[j] = f2h_bits(U[(size_t)(kb + j) * 4096 + g]);
  ((uint4*)Up)[idx] = *(const uint4*)tmp;
}

// ---- Phase B: persistent recurrent kernel ---------------------------------

#define OUT_HS 33554432   // 64*512*1024

__global__ __launch_bounds__(256, 2) void lstm_rec_kernel(
    const unsigned short* __restrict__ xh,   // [64][512][512] f16
    const unsigned short* __restrict__ Wp,   // packed f16
    const unsigned short* __restrict__ Up,   // packed f16
    const float* __restrict__ bias,          // [4096]
    float* __restrict__ out,
    unsigned short* __restrict__ hb,         // [2][64][1024] f16 (double-buffered)
    unsigned int* __restrict__ cnt)          // [4][32] group counters
{
  __shared__ unsigned short lx[16 * 520];    // x_t tile, rows padded +8 (2-way banks)
  __shared__ unsigned short lh[16 * 1032];   // h tile,  rows padded +8
  __shared__ float gl[4][16][16];            // gate exchange

  const int tid  = threadIdx.x;
  const int lane = tid & 63;
  const int wq   = tid >> 6;                 // wave id == gate section q (i,f,g,o)
  const int m    = lane & 15;
  const int quad = lane >> 4;

  // blockIdx -> (group, jt) with XCD-pairing swizzle (perf-only heuristic)
  const int bx  = blockIdx.x;
  const int x8  = bx & 7;
  const int grp = x8 >> 1;                            // 0..3  batch group
  const int jt  = ((bx >> 3) << 1) | (x8 & 1);        // 0..63 h-column tile
  const int b0  = grp * 16;
  const int T   = wq * 64 + jt;

  // Register-resident W fragments (128 VGPRs) and U fragments (64 VGPRs):
  // survives the per-step L2 invalidate from the coherence fences.
  f16x8 wf[32];
  {
    const f16x8* src = (const f16x8*)Wp + (size_t)T * 2048 + lane;
#pragma unroll
    for (int kt = 0; kt < 32; ++kt) wf[kt] = src[kt * 64];
  }
  f16x8 uf[16];
  {
    const f16x8* src = (const f16x8*)Up + (size_t)T * 1024 + lane;
#pragma unroll
    for (int k2 = 0; k2 < 16; ++k2) uf[k2] = src[k2 * 64];
  }
  const float bias_v = bias[wq * 1024 + jt * 16 + m];

  // epilogue mapping: thread <-> (batch row, column) matching C/D layout
  const int eb = tid >> 4, ej = tid & 15;
  const int b_out = b0 + eb;
  const int j_out = jt * 16 + ej;
  float c = 0.f;

  unsigned int* my_cnt = cnt + grp * 32;     // 128B-separated per-group counter

  for (int t = 0; t < 512; ++t) {
    // Stage x_t -> LDS. Safe before the group barrier completes: previous-step
    // lx reads all finished before the previous end-of-step __syncthreads.
    {
      const uint2* src = (const uint2*)xh;
#pragma unroll
      for (int i = 0; i < 8; ++i) {
        int idx = tid + i * 256;             // [0,2048)
        int row = idx >> 7, off = idx & 127;
        *(uint2*)&lx[row * 520 + off * 4] =
            src[(size_t)((b0 + row) * 512 + t) * 128 + off];
      }
    }
    __syncthreads();                         // S1: lx ready (+post-spin barrier for t>0)
    if (t > 0) __threadfence();              // acquire: invalidate stale L2 for hb

    f32x4 a0 = {bias_v, bias_v, bias_v, bias_v};
    f32x4 a1 = {0.f, 0.f, 0.f, 0.f};

    if (t > 0) {
      // h staging overlaps the x@U MFMA chain (compiler interleaves)
      {
        const uint2* src = (const uint2*)hb + ((t & 1) ? 16384 : 0) + b0 * 256;
#pragma unroll
        for (int i = 0; i < 16; ++i) {
          int idx = tid + i * 256;           // [0,4096)
          int row = idx >> 8, off = idx & 255;
          *(uint2*)&lh[row * 1032 + off * 4] = src[row * 256 + off];
        }
      }
#pragma unroll
      for (int k2 = 0; k2 < 16; ++k2) {
        f16x8 xa = *(const f16x8*)&lx[m * 520 + k2 * 32 + quad * 8];
        if (k2 & 1) a1 = __builtin_amdgcn_mfma_f32_16x16x32_f16(xa, uf[k2], a1, 0, 0, 0);
        else        a0 = __builtin_amdgcn_mfma_f32_16x16x32_f16(xa, uf[k2], a0, 0, 0, 0);
      }
      __syncthreads();                       // S2: lh ready
#pragma unroll
      for (int kt = 0; kt < 32; ++kt) {
        f16x8 ha = *(const f16x8*)&lh[m * 1032 + kt * 32 + quad * 8];
        if (kt & 1) a1 = __builtin_amdgcn_mfma_f32_16x16x32_f16(ha, wf[kt], a1, 0, 0, 0);
        else        a0 = __builtin_amdgcn_mfma_f32_16x16x32_f16(ha, wf[kt], a0, 0, 0, 0);
      }
    } else {
#pragma unroll
      for (int k2 = 0; k2 < 16; ++k2) {
        f16x8 xa = *(const f16x8*)&lx[m * 520 + k2 * 32 + quad * 8];
        if (k2 & 1) a1 = __builtin_amdgcn_mfma_f32_16x16x32_f16(xa, uf[k2], a1, 0, 0, 0);
        else        a0 = __builtin_amdgcn_mfma_f32_16x16x32_f16(xa, uf[k2], a0, 0, 0, 0);
      }
    }

    // C/D layout: col = lane&15, row = quad*4 + r
#pragma unroll
    for (int r = 0; r < 4; ++r) gl[wq][quad * 4 + r][m] = a0[r] + a1[r];
    __syncthreads();                         // S3: gates ready

    float iv = gl[0][eb][ej], fv = gl[1][eb][ej];
    float gv = gl[2][eb][ej], ov = gl[3][eb][ej];
    float ig = 1.f / (1.f + __expf(-iv));
    float fg = 1.f / (1.f + __expf(-fv));
    float og = 1.f / (1.f + __expf(-ov));
    float e2g = __expf(2.f * gv);
    float gg = 1.f - 2.f / (e2g + 1.f);      // tanh, inf-safe
    c = fg * c + ig * gg;
    float e2c = __expf(2.f * c);
    float tc = 1.f - 2.f / (e2c + 1.f);
    float h = og * tc;

    out[(size_t)b_out * (512 * 1024) + (size_t)t * 1024 + j_out] = h;
    hb[(((t + 1) & 1) ? 65536 : 0) + (b0 + eb) * 1024 + j_out] = f2h_bits(h);
    if (t == 511) {
      out[OUT_HS + b_out * 1024 + j_out] = h;
      out[OUT_HS + 65536 + b_out * 1024 + j_out] = c;
    }

    if (t < 511) {
      __threadfence();                       // release: h stores -> coherence point
      __syncthreads();                       // all threads' stores fenced
      if (tid == 0) {
        atomicAdd(my_cnt, 1u);
        unsigned int target = 64u * (unsigned int)(t + 1);
        while (__hip_atomic_load(my_cnt, __ATOMIC_RELAXED, __HIP_MEMORY_SCOPE_AGENT) < target) {
          __builtin_amdgcn_s_sleep(4);
        }
      }
      // next iteration's S1 holds the other threads until tid 0 exits the spin
    }
  }
}

// ---- host-side launch -----------------------------------------------------

extern "C" void kernel_launch(void* const* d_in, const int* in_sizes, int n_in,
                              void* d_out, int out_size, void* d_ws, size_t ws_size,
                              hipStream_t stream) {
  const float* x    = (const float*)d_in[0];   // 64*512*512
  const float* U    = (const float*)d_in[1];   // 512*4096
  const float* W    = (const float*)d_in[2];   // 1024*4096
  const float* bias = (const float*)d_in[3];   // 4096
  float* out = (float*)d_out;

  char* p = (char*)d_ws;
  unsigned short* xh = (unsigned short*)p; p += (size_t)64 * 512 * 512 * 2;   // 33.5 MB
  unsigned short* Wp = (unsigned short*)p; p += (size_t)4096 * 1024 * 2;      //  8.4 MB
  unsigned short* Up = (unsigned short*)p; p += (size_t)4096 * 512 * 2;       //  4.2 MB
  unsigned short* hb = (unsigned short*)p; p += (size_t)2 * 64 * 1024 * 2;    //  256 KB
  unsigned int* cnt  = (unsigned int*)p;                                      //  512 B

  hipMemsetAsync(cnt, 0, 4 * 32 * sizeof(unsigned int), stream);
  cast_x_kernel<<<16384, 256, 0, stream>>>(x, xh);
  pack_W_kernel<<<2048, 256, 0, stream>>>(W, Wp);
  pack_U_kernel<<<1024, 256, 0, stream>>>(U, Up);
  lstm_rec_kernel<<<256, 256, 0, stream>>>(xh, Wp, Up, bias, out, hb, cnt);
}

// Round 2
// 2744.496 us; speedup vs baseline: 8.1572x; 8.1572x over previous
//
#include <hip/hip_runtime.h>

// LSTM: x[64][512][512] fp32, U[512][4096], W[1024][4096], bias[4096]
// out = hidden_seq[64][512][1024] fp32 ++ h_T[64][1024] ++ c_T[64][1024]
//
// Phase A (parallel): cast x->f16; pack W,U into per-lane MFMA B-fragment order.
// Phase B (persistent, 256 WGs x 256 thr): 4 batch-groups x 16 batches; each group
//  = 64 WGs (one 16-wide h-column tile each); wave q computes gate section q.
//  Sync redesign (R2): per-WG flag array + sc1 (agent-scope relaxed atomic)
//  h exchange. NO threadfence (no buffer_wbl2/inv), NO contended atomicAdd.
//  Release = h stores -> s_waitcnt vmcnt(0) -> __syncthreads -> flag store.
//  Acquire = poll flag (dependent branch) -> coherent h loads.

typedef _Float16 f16x8 __attribute__((ext_vector_type(8)));
typedef float f32x4 __attribute__((ext_vector_type(4)));

__device__ __forceinline__ unsigned short f2h_bits(float f) {
  union { _Float16 h; unsigned short u; } cv;
  cv.h = (_Float16)f;
  return cv.u;
}
__device__ __forceinline__ unsigned int aload(unsigned int* p) {
  return __hip_atomic_load(p, __ATOMIC_RELAXED, __HIP_MEMORY_SCOPE_AGENT);
}
__device__ __forceinline__ void astore(unsigned int* p, unsigned int v) {
  __hip_atomic_store(p, v, __ATOMIC_RELAXED, __HIP_MEMORY_SCOPE_AGENT);
}
__device__ __forceinline__ unsigned long long aload64(unsigned long long* p) {
  return __hip_atomic_load(p, __ATOMIC_RELAXED, __HIP_MEMORY_SCOPE_AGENT);
}

// ---- Phase A kernels ------------------------------------------------------

__global__ void cast_x_kernel(const float* __restrict__ x, unsigned short* __restrict__ xh) {
  int i = blockIdx.x * 256 + threadIdx.x;            // [0, 4194304)
  float4 v = ((const float4*)x)[i];
  ushort4 o;
  o.x = f2h_bits(v.x); o.y = f2h_bits(v.y);
  o.z = f2h_bits(v.z); o.w = f2h_bits(v.w);
  ((ushort4*)xh)[i] = o;
}

// Wp[((T*32+kt)*64+l)*8 + j] = f16(W[kt*32 + (l>>4)*8 + j][(T>>6)*1024 + (T&63)*16 + (l&15)])
__global__ void pack_W_kernel(const float* __restrict__ W, unsigned short* __restrict__ Wp) {
  int idx = blockIdx.x * 256 + threadIdx.x;          // [0, 524288)
  int l  = idx & 63;
  int kt = (idx >> 6) & 31;
  int T  = idx >> 11;                                // 0..255
  int q = T >> 6, jt = T & 63;
  int g  = q * 1024 + jt * 16 + (l & 15);
  int kb = kt * 32 + ((l >> 4) << 3);
  unsigned short tmp[8];
#pragma unroll
  for (int j = 0; j < 8; ++j) tmp[j] = f2h_bits(W[(size_t)(kb + j) * 4096 + g]);
  ((uint4*)Wp)[idx] = *(const uint4*)tmp;
}

__global__ void pack_U_kernel(const float* __restrict__ U, unsigned short* __restrict__ Up) {
  int idx = blockIdx.x * 256 + threadIdx.x;          // [0, 262144)
  int l  = idx & 63;
  int kt = (idx >> 6) & 15;
  int T  = idx >> 10;                                // 0..255
  int q = T >> 6, jt = T & 63;
  int g  = q * 1024 + jt * 16 + (l & 15);
  int kb = kt * 32 + ((l >> 4) << 3);
  unsigned short tmp[8];
#pragma unroll
  for (int j = 0; j < 8; ++j) tmp[j] = f2h_bits(U[(size_t)(kb + j) * 4096 + g]);
  ((uint4*)Up)[idx] = *(const uint4*)tmp;
}

// ---- Phase B: persistent recurrent kernel ---------------------------------

#define OUT_HS 33554432   // 64*512*1024

__global__ __launch_bounds__(256, 1) void lstm_rec_kernel(
    const unsigned short* __restrict__ xh,   // [64][512][512] f16
    const unsigned short* __restrict__ Wp,   // packed f16
    const unsigned short* __restrict__ Up,   // packed f16
    const float* __restrict__ bias,          // [4096]
    float* __restrict__ out,
    unsigned int* hb,                        // [4 grp][2 slot][16][1024] f16 (as uint pairs)
    unsigned int* flags)                     // [4 grp][64 producers]
{
  __shared__ unsigned short lx[16 * 520];    // x_t tile, rows padded +8
  __shared__ unsigned short lh[16 * 1032];   // h tile,  rows padded +8
  __shared__ float gl[4][16][16];            // gate exchange

  const int tid  = threadIdx.x;
  const int lane = tid & 63;
  const int wq   = tid >> 6;                 // wave id == gate section (i,f,g,o)
  const int m    = lane & 15;
  const int quad = lane >> 4;

  const int bx  = blockIdx.x;
  const int x8  = bx & 7;
  const int grp = x8 >> 1;                            // 0..3 batch group
  const int jt  = ((bx >> 3) << 1) | (x8 & 1);        // 0..63 h-column tile
  const int b0  = grp * 16;
  const int T   = wq * 64 + jt;

  // Register/AGPR-resident weight fragments
  f16x8 wf[32];
  {
    const f16x8* src = (const f16x8*)Wp + (size_t)T * 2048 + lane;
#pragma unroll
    for (int kt = 0; kt < 32; ++kt) wf[kt] = src[kt * 64];
  }
  f16x8 uf[16];
  {
    const f16x8* src = (const f16x8*)Up + (size_t)T * 1024 + lane;
#pragma unroll
    for (int k2 = 0; k2 < 16; ++k2) uf[k2] = src[k2 * 64];
  }
  const float bias_v = bias[wq * 1024 + jt * 16 + m];

  const int eb = tid >> 4, ej = tid & 15;    // epilogue: batch row / column
  const int b_out = b0 + eb;
  const int j_out = jt * 16 + ej;
  float c = 0.f;

  unsigned int* my_flag  = flags + grp * 64 + jt;
  unsigned int* grp_flags = flags + grp * 64;

  for (int t = 0; t < 512; ++t) {
    // Stage x_t -> LDS (plain cached loads; read-only data)
    {
      const uint2* src = (const uint2*)xh;
#pragma unroll
      for (int i = 0; i < 8; ++i) {
        int idx = tid + i * 256;             // [0,2048)
        int row = idx >> 7, off = idx & 127;
        *(uint2*)&lx[row * 520 + off * 4] =
            src[(size_t)((b0 + row) * 512 + t) * 128 + off];
      }
    }
    __syncthreads();                         // S1: lx ready

    f32x4 a0 = {bias_v, bias_v, bias_v, bias_v};
    f32x4 a1 = {0.f, 0.f, 0.f, 0.f};

    // x@U — independent of h, runs before the flag wait (overlap)
#pragma unroll
    for (int k2 = 0; k2 < 16; ++k2) {
      f16x8 xa = *(const f16x8*)&lx[m * 520 + k2 * 32 + quad * 8];
      if (k2 & 1) a1 = __builtin_amdgcn_mfma_f32_16x16x32_f16(xa, uf[k2], a1, 0, 0, 0);
      else        a0 = __builtin_amdgcn_mfma_f32_16x16x32_f16(xa, uf[k2], a0, 0, 0, 0);
    }

    if (t > 0) {
      // Wait for all 64 producers of this group to have published h(t-1).
      if (wq == 0) {
        unsigned int* f = grp_flags + lane;  // one lane per producer
        while (aload(f) < (unsigned int)t) __builtin_amdgcn_s_sleep(1);
      }
      __syncthreads();                       // B1: flags confirmed

      // Stage h(t-1) -> LDS via coherent (sc1) loads; regs first to pipeline
      {
        unsigned long long* src = (unsigned long long*)hb +
            (size_t)(grp * 2 + ((t - 1) & 1)) * 4096;
        unsigned long long u[16];
#pragma unroll
        for (int i = 0; i < 16; ++i) u[i] = aload64(src + tid + i * 256);
#pragma unroll
        for (int i = 0; i < 16; ++i) {
          int idx = tid + i * 256;           // [0,4096)
          int row = idx >> 8, off = idx & 255;
          *(unsigned long long*)&lh[row * 1032 + off * 4] = u[i];
        }
      }
      __syncthreads();                       // B2: lh ready

#pragma unroll
      for (int kt = 0; kt < 32; ++kt) {
        f16x8 ha = *(const f16x8*)&lh[m * 1032 + kt * 32 + quad * 8];
        if (kt & 1) a1 = __builtin_amdgcn_mfma_f32_16x16x32_f16(ha, wf[kt], a1, 0, 0, 0);
        else        a0 = __builtin_amdgcn_mfma_f32_16x16x32_f16(ha, wf[kt], a0, 0, 0, 0);
      }
    }

    // C/D layout: col = lane&15, row = quad*4 + r
#pragma unroll
    for (int r = 0; r < 4; ++r) gl[wq][quad * 4 + r][m] = a0[r] + a1[r];
    __syncthreads();                         // S3: gates ready

    float iv = gl[0][eb][ej], fv = gl[1][eb][ej];
    float gv = gl[2][eb][ej], ov = gl[3][eb][ej];
    float ig = 1.f / (1.f + __expf(-iv));
    float fg = 1.f / (1.f + __expf(-fv));
    float og = 1.f / (1.f + __expf(-ov));
    float e2g = __expf(2.f * gv);
    float gg = 1.f - 2.f / (e2g + 1.f);      // tanh, inf-safe
    c = fg * c + ig * gg;
    float e2c = __expf(2.f * c);
    float tc = 1.f - 2.f / (e2c + 1.f);
    float h = og * tc;

    out[(size_t)b_out * (512 * 1024) + (size_t)t * 1024 + j_out] = h;
    if (t == 511) {
      out[OUT_HS + b_out * 1024 + j_out] = h;
      out[OUT_HS + 65536 + b_out * 1024 + j_out] = c;
    } else {
      // Publish h(t) via coherent stores: pack 2 f16 per uint (even ej stores)
      unsigned int hbits = (unsigned int)f2h_bits(h);
      unsigned int nbits = (unsigned int)__shfl_down((int)hbits, 1);
      if ((ej & 1) == 0) {
        unsigned int* dst = hb + (size_t)(grp * 2 + (t & 1)) * 8192 +
                            eb * 512 + jt * 8 + (ej >> 1);
        astore(dst, hbits | (nbits << 16));
      }
      asm volatile("s_waitcnt vmcnt(0)" ::: "memory");  // per-wave: h stores visible
      __syncthreads();                       // S4: all waves' h stores visible
      if (tid == 0) astore(my_flag, (unsigned int)(t + 1));
    }
  }
}

// ---- host-side launch -----------------------------------------------------

extern "C" void kernel_launch(void* const* d_in, const int* in_sizes, int n_in,
                              void* d_out, int out_size, void* d_ws, size_t ws_size,
                              hipStream_t stream) {
  const float* x    = (const float*)d_in[0];   // 64*512*512
  const float* U    = (const float*)d_in[1];   // 512*4096
  const float* W    = (const float*)d_in[2];   // 1024*4096
  const float* bias = (const float*)d_in[3];   // 4096
  float* out = (float*)d_out;

  char* p = (char*)d_ws;
  unsigned short* xh = (unsigned short*)p; p += (size_t)64 * 512 * 512 * 2;   // 33.5 MB
  unsigned short* Wp = (unsigned short*)p; p += (size_t)4096 * 1024 * 2;      //  8.4 MB
  unsigned short* Up = (unsigned short*)p; p += (size_t)4096 * 512 * 2;       //  4.2 MB
  unsigned int*   hb = (unsigned int*)p;   p += (size_t)4 * 2 * 16 * 1024 * 2;// 256 KB
  unsigned int* flags = (unsigned int*)p;                                     //  1 KB

  hipMemsetAsync(flags, 0, 4 * 64 * sizeof(unsigned int), stream);
  cast_x_kernel<<<16384, 256, 0, stream>>>(x, xh);
  pack_W_kernel<<<2048, 256, 0, stream>>>(W, Wp);
  pack_U_kernel<<<1024, 256, 0, stream>>>(U, Up);
  lstm_rec_kernel<<<256, 256, 0, stream>>>(xh, Wp, Up, bias, out, hb, flags);
}

// Round 3
// 1915.219 us; speedup vs baseline: 11.6893x; 1.4330x over previous
//
#include <hip/hip_runtime.h>

// LSTM: x[64][512][512] fp32, U[512][4096], W[1024][4096], bias[4096]
// out = hidden_seq[64][512][1024] fp32 ++ h_T[64][1024] ++ c_T[64][1024]
//
// Phase A (parallel): cast x->f16; pack W,U into per-lane MFMA B-fragment order.
// Phase B (persistent, 256 WGs x 256 thr): 4 batch-groups x 16 batches; each group
//  = 64 WGs (one 16-wide h-column tile each); wave q computes gate section q.
// R3: critical-path strip-down.
//  - lx double-buffered; x(t+1) global loads issued right after S1, shadowed by
//    the flag poll + h load; written to the other LDS buffer after h@W MFMAs.
//  - epilogue: out store FIRST, then hb publish -> per-wave vmcnt(0) -> per-wave
//    flag store (no extra __syncthreads, no tid0 handoff, HBM ack off flag path).
//  - all 4 waves poll the 256 per-wave flags directly.

typedef _Float16 f16x8 __attribute__((ext_vector_type(8)));
typedef float f32x4 __attribute__((ext_vector_type(4)));

__device__ __forceinline__ unsigned short f2h_bits(float f) {
  union { _Float16 h; unsigned short u; } cv;
  cv.h = (_Float16)f;
  return cv.u;
}
__device__ __forceinline__ unsigned int aload(unsigned int* p) {
  return __hip_atomic_load(p, __ATOMIC_RELAXED, __HIP_MEMORY_SCOPE_AGENT);
}
__device__ __forceinline__ void astore(unsigned int* p, unsigned int v) {
  __hip_atomic_store(p, v, __ATOMIC_RELAXED, __HIP_MEMORY_SCOPE_AGENT);
}
__device__ __forceinline__ unsigned long long aload64(unsigned long long* p) {
  return __hip_atomic_load(p, __ATOMIC_RELAXED, __HIP_MEMORY_SCOPE_AGENT);
}

// ---- Phase A kernels ------------------------------------------------------

__global__ void cast_x_kernel(const float* __restrict__ x, unsigned short* __restrict__ xh) {
  int i = blockIdx.x * 256 + threadIdx.x;            // [0, 4194304)
  float4 v = ((const float4*)x)[i];
  ushort4 o;
  o.x = f2h_bits(v.x); o.y = f2h_bits(v.y);
  o.z = f2h_bits(v.z); o.w = f2h_bits(v.w);
  ((ushort4*)xh)[i] = o;
}

// Wp[((T*32+kt)*64+l)*8 + j] = f16(W[kt*32 + (l>>4)*8 + j][(T>>6)*1024 + (T&63)*16 + (l&15)])
__global__ void pack_W_kernel(const float* __restrict__ W, unsigned short* __restrict__ Wp) {
  int idx = blockIdx.x * 256 + threadIdx.x;          // [0, 524288)
  int l  = idx & 63;
  int kt = (idx >> 6) & 31;
  int T  = idx >> 11;                                // 0..255
  int q = T >> 6, jt = T & 63;
  int g  = q * 1024 + jt * 16 + (l & 15);
  int kb = kt * 32 + ((l >> 4) << 3);
  unsigned short tmp[8];
#pragma unroll
  for (int j = 0; j < 8; ++j) tmp[j] = f2h_bits(W[(size_t)(kb + j) * 4096 + g]);
  ((uint4*)Wp)[idx] = *(const uint4*)tmp;
}

__global__ void pack_U_kernel(const float* __restrict__ U, unsigned short* __restrict__ Up) {
  int idx = blockIdx.x * 256 + threadIdx.x;          // [0, 262144)
  int l  = idx & 63;
  int kt = (idx >> 6) & 15;
  int T  = idx >> 10;                                // 0..255
  int q = T >> 6, jt = T & 63;
  int g  = q * 1024 + jt * 16 + (l & 15);
  int kb = kt * 32 + ((l >> 4) << 3);
  unsigned short tmp[8];
#pragma unroll
  for (int j = 0; j < 8; ++j) tmp[j] = f2h_bits(U[(size_t)(kb + j) * 4096 + g]);
  ((uint4*)Up)[idx] = *(const uint4*)tmp;
}

// ---- Phase B: persistent recurrent kernel ---------------------------------

#define OUT_HS 33554432   // 64*512*1024

__global__ __launch_bounds__(256, 1) void lstm_rec_kernel(
    const unsigned short* __restrict__ xh,   // [64][512][512] f16
    const unsigned short* __restrict__ Wp,   // packed f16
    const unsigned short* __restrict__ Up,   // packed f16
    const float* __restrict__ bias,          // [4096]
    float* __restrict__ out,
    unsigned int* hb,                        // [4 grp][2 slot][16][1024] f16 (uint pairs)
    unsigned int* flags)                     // [4 grp][64 wg][4 wave]
{
  __shared__ unsigned short lx[2][16 * 520]; // x tiles, rows padded +8, double-buffered
  __shared__ unsigned short lh[16 * 1032];   // h tile, rows padded +8
  __shared__ float gl[4][16][16];            // gate exchange

  const int tid  = threadIdx.x;
  const int lane = tid & 63;
  const int wq   = tid >> 6;                 // wave id == gate section (i,f,g,o)
  const int m    = lane & 15;
  const int quad = lane >> 4;

  const int bx  = blockIdx.x;
  const int x8  = bx & 7;
  const int grp = x8 >> 1;                            // 0..3 batch group
  const int jt  = ((bx >> 3) << 1) | (x8 & 1);        // 0..63 h-column tile
  const int b0  = grp * 16;
  const int T   = wq * 64 + jt;

  // Register/AGPR-resident weight fragments
  f16x8 wf[32];
  {
    const f16x8* src = (const f16x8*)Wp + (size_t)T * 2048 + lane;
#pragma unroll
    for (int kt = 0; kt < 32; ++kt) wf[kt] = src[kt * 64];
  }
  f16x8 uf[16];
  {
    const f16x8* src = (const f16x8*)Up + (size_t)T * 1024 + lane;
#pragma unroll
    for (int k2 = 0; k2 < 16; ++k2) uf[k2] = src[k2 * 64];
  }
  const float bias_v = bias[wq * 1024 + jt * 16 + m];

  const int eb = tid >> 4, ej = tid & 15;    // epilogue: batch row / column
  const int b_out = b0 + eb;
  const int j_out = jt * 16 + ej;
  float c = 0.f;

  unsigned int* my_flag   = flags + grp * 256 + jt * 4 + wq;
  unsigned int* grp_flags = flags + grp * 256;

  const uint2* xsrc = (const uint2*)xh;

  // Prologue: stage x(0) into lx[0]
  uint2 xr[8];
#pragma unroll
  for (int i = 0; i < 8; ++i) {
    int idx = tid + i * 256, row = idx >> 7, off = idx & 127;
    xr[i] = xsrc[(size_t)((b0 + row) * 512 + 0) * 128 + off];
  }
#pragma unroll
  for (int i = 0; i < 8; ++i) {
    int idx = tid + i * 256, row = idx >> 7, off = idx & 127;
    *(uint2*)&lx[0][row * 520 + off * 4] = xr[i];
  }

  for (int t = 0; t < 512; ++t) {
    __syncthreads();                         // S1: lx[t&1] ready; gl(t-1) reads done

    // Prefetch x(t+1) into regs — shadowed by poll + h load below.
    if (t < 511) {
#pragma unroll
      for (int i = 0; i < 8; ++i) {
        int idx = tid + i * 256, row = idx >> 7, off = idx & 127;
        xr[i] = xsrc[(size_t)((b0 + row) * 512 + (t + 1)) * 128 + off];
      }
    }

    f32x4 a0 = {bias_v, bias_v, bias_v, bias_v};
    f32x4 a1 = {0.f, 0.f, 0.f, 0.f};

    const unsigned short* lxt = lx[t & 1];
#pragma unroll
    for (int k2 = 0; k2 < 16; ++k2) {
      f16x8 xa = *(const f16x8*)&lxt[m * 520 + k2 * 32 + quad * 8];
      if (k2 & 1) a1 = __builtin_amdgcn_mfma_f32_16x16x32_f16(xa, uf[k2], a1, 0, 0, 0);
      else        a0 = __builtin_amdgcn_mfma_f32_16x16x32_f16(xa, uf[k2], a0, 0, 0, 0);
    }

    if (t > 0) {
      // All waves poll all 256 per-wave flags of the group.
      unsigned int* f = grp_flags + lane;
      while (true) {
        unsigned int v0 = aload(f);
        unsigned int v1 = aload(f + 64);
        unsigned int v2 = aload(f + 128);
        unsigned int v3 = aload(f + 192);
        unsigned int mn = v0 < v1 ? v0 : v1;
        unsigned int mn2 = v2 < v3 ? v2 : v3;
        mn = mn < mn2 ? mn : mn2;
        if (!__any((int)(mn < (unsigned int)t))) break;
        __builtin_amdgcn_s_sleep(1);
      }

      // Stage h(t-1) -> regs -> LDS (coherent loads)
      unsigned long long* src = (unsigned long long*)hb +
          (size_t)(grp * 2 + ((t - 1) & 1)) * 4096;
      unsigned long long u[16];
#pragma unroll
      for (int i = 0; i < 16; ++i) u[i] = aload64(src + tid + i * 256);
#pragma unroll
      for (int i = 0; i < 16; ++i) {
        int idx = tid + i * 256, row = idx >> 8, off = idx & 255;
        *(unsigned long long*)&lh[row * 1032 + off * 4] = u[i];
      }
      __syncthreads();                       // B2: lh ready

#pragma unroll
      for (int kt = 0; kt < 32; ++kt) {
        f16x8 ha = *(const f16x8*)&lh[m * 1032 + kt * 32 + quad * 8];
        if (kt & 1) a1 = __builtin_amdgcn_mfma_f32_16x16x32_f16(ha, wf[kt], a1, 0, 0, 0);
        else        a0 = __builtin_amdgcn_mfma_f32_16x16x32_f16(ha, wf[kt], a0, 0, 0, 0);
      }
    }

    // Write next x tile into the other LDS buffer (loads long since complete).
    if (t < 511) {
#pragma unroll
      for (int i = 0; i < 8; ++i) {
        int idx = tid + i * 256, row = idx >> 7, off = idx & 127;
        *(uint2*)&lx[(t + 1) & 1][row * 520 + off * 4] = xr[i];
      }
    }

    // C/D layout: col = lane&15, row = quad*4 + r
#pragma unroll
    for (int r = 0; r < 4; ++r) gl[wq][quad * 4 + r][m] = a0[r] + a1[r];
    __syncthreads();                         // S3: gates ready

    float iv = gl[0][eb][ej], fv = gl[1][eb][ej];
    float gv = gl[2][eb][ej], ov = gl[3][eb][ej];
    float ig = 1.f / (1.f + __expf(-iv));
    float fg = 1.f / (1.f + __expf(-fv));
    float og = 1.f / (1.f + __expf(-ov));
    float e2g = __expf(2.f * gv);
    float gg = 1.f - 2.f / (e2g + 1.f);      // tanh, inf-safe
    c = fg * c + ig * gg;
    float e2c = __expf(2.f * c);
    float tc = 1.f - 2.f / (e2c + 1.f);
    float h = og * tc;

    out[(size_t)b_out * (512 * 1024) + (size_t)t * 1024 + j_out] = h;
    if (t == 511) {
      out[OUT_HS + b_out * 1024 + j_out] = h;
      out[OUT_HS + 65536 + b_out * 1024 + j_out] = c;
    } else {
      // Publish h(t): pack 2 f16 per uint (even ej stores both halves).
      unsigned int hbits = (unsigned int)f2h_bits(h);
      unsigned int nbits = (unsigned int)__shfl_down((int)hbits, 1);
      if ((ej & 1) == 0) {
        unsigned int* dst = hb + (size_t)(grp * 2 + (t & 1)) * 8192 +
                            eb * 512 + jt * 8 + (ej >> 1);
        astore(dst, hbits | (nbits << 16));
      }
      asm volatile("s_waitcnt vmcnt(0)" ::: "memory");  // wave's out+hb stores acked
      if (lane == 0) astore(my_flag, (unsigned int)(t + 1));  // per-wave flag
    }
  }
}

// ---- host-side launch -----------------------------------------------------

extern "C" void kernel_launch(void* const* d_in, const int* in_sizes, int n_in,
                              void* d_out, int out_size, void* d_ws, size_t ws_size,
                              hipStream_t stream) {
  const float* x    = (const float*)d_in[0];   // 64*512*512
  const float* U    = (const float*)d_in[1];   // 512*4096
  const float* W    = (const float*)d_in[2];   // 1024*4096
  const float* bias = (const float*)d_in[3];   // 4096
  float* out = (float*)d_out;

  char* p = (char*)d_ws;
  unsigned short* xh = (unsigned short*)p; p += (size_t)64 * 512 * 512 * 2;   // 33.5 MB
  unsigned short* Wp = (unsigned short*)p; p += (size_t)4096 * 1024 * 2;      //  8.4 MB
  unsigned short* Up = (unsigned short*)p; p += (size_t)4096 * 512 * 2;       //  4.2 MB
  unsigned int*   hb = (unsigned int*)p;   p += (size_t)4 * 2 * 16 * 1024 * 2;// 256 KB
  unsigned int* flags = (unsigned int*)p;                                     //  4 KB

  hipMemsetAsync(flags, 0, 4 * 256 * sizeof(unsigned int), stream);
  cast_x_kernel<<<16384, 256, 0, stream>>>(x, xh);
  pack_W_kernel<<<2048, 256, 0, stream>>>(W, Wp);
  pack_U_kernel<<<1024, 256, 0, stream>>>(U, Up);
  lstm_rec_kernel<<<256, 256, 0, stream>>>(xh, Wp, Up, bias, out, hb, flags);
}